// Round 5
// baseline (572.191 us; speedup 1.0000x reference)
//
#include <hip/hip_runtime.h>
#include <math.h>

#define N 8192
#define FIN 512
#define FOUT 256
#define NEGV (-9e15f)
#define NCAND 16
#define HMAX 64

typedef long long ll;

// ---------------- kernel 0: mui softmax + derived params + zero accumulators ----------------
__global__ void params_kernel(const float* __restrict__ Mui, float* __restrict__ params,
                              float* __restrict__ wfrob2, unsigned* __restrict__ hnmaxbits) {
    if (threadIdx.x == 0) {
        float m = Mui[0];
        for (int i = 1; i < 6; ++i) m = fmaxf(m, Mui[i]);
        float e[6], s = 0.f;
        for (int i = 0; i < 6; ++i) { e[i] = expf(Mui[i] - m); s += e[i]; }
        float mui[6];
        for (int i = 0; i < 6; ++i) mui[i] = e[i] / s;
        params[0] = mui[0] + mui[1] + mui[2] + mui[3];                    // a (G coefficient)
        params[1] = 0.5f * (mui[0] + mui[1]) + 1.0f * (mui[2] + mui[3]); // additive const
        params[2] = 256.0f * mui[4];                                      // D*mui4
        params[3] = 256.0f * mui[5];                                      // D*mui5
        *wfrob2 = 0.f;
        *hnmaxbits = 0u;
    }
}

// ---------------- kernel 1: ||W||_F^2 + extract W[:,1] ----------------
__global__ __launch_bounds__(256) void wfrob_kernel(const float* __restrict__ W,
                                                    float* __restrict__ wfrob2,
                                                    float* __restrict__ wcol1) {
    int idx4 = (blockIdx.x * 256 + threadIdx.x) * 4;   // FIN*FOUT = 131072 elems, 128 blocks
    float4 v = *(const float4*)&W[idx4];
    if ((idx4 & 255) == 0) wcol1[idx4 >> 8] = v.y;     // column 1 of row idx4>>8
    float s = v.x * v.x + v.y * v.y + v.z * v.z + v.w * v.w;
#pragma unroll
    for (int off = 1; off < 64; off <<= 1) s += __shfl_xor(s, off, 64);
    if ((threadIdx.x & 63) == 0) atomicAdd(wfrob2, s);
}

// ---------------- kernel 2: per-row t1 (GEMV vs W[:,1]), ||h_i||, factors ----------------
__global__ __launch_bounds__(256) void rowstats_kernel(
    const float* __restrict__ h, const float* __restrict__ params,
    const float* __restrict__ wcol1,
    float* __restrict__ t1a, float* __restrict__ x1, float* __restrict__ x2,
    float* __restrict__ w1, float* __restrict__ w2,
    float* __restrict__ hn, unsigned* __restrict__ hnmaxbits) {
    __shared__ float wc[FIN];
    const int t = threadIdx.x;
    ((float2*)wc)[t] = ((const float2*)wcol1)[t];
    __syncthreads();
    const int w = t >> 6, lane = t & 63;
    const int i = blockIdx.x * 4 + w;
    const float4* hp = (const float4*)&h[(ll)i * FIN + lane * 8];
    float4 a = hp[0], b = hp[1];
    const float4* wv = (const float4*)&wc[lane * 8];
    float4 c0 = wv[0], c1 = wv[1];
    float s = a.x * c0.x + a.y * c0.y + a.z * c0.z + a.w * c0.w
            + b.x * c1.x + b.y * c1.y + b.z * c1.z + b.w * c1.w;
    float n = a.x * a.x + a.y * a.y + a.z * a.z + a.w * a.w
            + b.x * b.x + b.y * b.y + b.z * b.z + b.w * b.w;
#pragma unroll
    for (int off = 1; off < 64; off <<= 1) {
        s += __shfl_xor(s, off, 64);
        n += __shfl_xor(n, off, 64);
    }
    if (lane == 0) {
        float t1 = s * s;
        t1a[i] = t1;
        x1[i] = expf(0.5f * t1);
        x2[i] = expf(t1);
        w1[i] = params[2] * expf(-0.5f * t1);
        w2[i] = params[3] * expf(-t1);
        float nr = sqrtf(n);
        hn[i] = nr;
        atomicMax(hnmaxbits, __float_as_uint(nr));   // nr > 0 -> bit-monotone
    }
}

// ---------------- kernel 3a: per-slice top-16 (64 blocks x 128 rows, 1 wave) ----------------
__global__ __launch_bounds__(64) void topk1_kernel(const float* __restrict__ t1a,
                                                   float* __restrict__ o1v,
                                                   int* __restrict__ o1i) {
    const int l = threadIdx.x;
    const int base = blockIdx.x * 128;
    float v0 = t1a[base + l], v1 = t1a[base + 64 + l];
    int i0 = base + l, i1 = base + 64 + l;
    for (int r = 0; r < NCAND; ++r) {
        float mv; int mi;
        if (v0 >= v1) { mv = v0; mi = i0; } else { mv = v1; mi = i1; }
#pragma unroll
        for (int off = 1; off < 64; off <<= 1) {
            float ov = __shfl_xor(mv, off, 64);
            int   oi = __shfl_xor(mi, off, 64);
            if (ov > mv || (ov == mv && oi < mi)) { mv = ov; mi = oi; }
        }
        if (mi == i0) v0 = -2.f;
        if (mi == i1) v1 = -2.f;
        if (l == r) { o1v[blockIdx.x * NCAND + r] = mv; o1i[blockIdx.x * NCAND + r] = mi; }
    }
}

// ---------------- kernel 3b: global top-16 from 1024 candidates (1 block) ----------------
__global__ __launch_bounds__(1024) void topk2_kernel(
    const float* __restrict__ o1v, const int* __restrict__ o1i,
    const float* __restrict__ t1a, const float* __restrict__ x1, const float* __restrict__ x2,
    int* __restrict__ cidx, float* __restrict__ ct1, float* __restrict__ cx1,
    float* __restrict__ cx2, float* __restrict__ ubx, int* __restrict__ hardcnt) {
    __shared__ float lv[16];
    __shared__ int li[16];
    __shared__ float bvs;
    __shared__ int bis;
    const int t = threadIdx.x;
    float v = o1v[t];
    int idx = o1i[t];
    for (int r = 0; r < NCAND; ++r) {
        float mv = v; int mi = idx;
#pragma unroll
        for (int off = 1; off < 64; off <<= 1) {
            float ov = __shfl_xor(mv, off, 64);
            int   oi = __shfl_xor(mi, off, 64);
            if (ov > mv || (ov == mv && oi < mi)) { mv = ov; mi = oi; }
        }
        if ((t & 63) == 0) { lv[t >> 6] = mv; li[t >> 6] = mi; }
        __syncthreads();
        if (t < 64) {
            float m2 = (t < 16) ? lv[t] : -3.f;
            int   i2 = (t < 16) ? li[t] : -1;
#pragma unroll
            for (int off = 1; off < 16; off <<= 1) {
                float ov = __shfl_xor(m2, off, 64);
                int   oi = __shfl_xor(i2, off, 64);
                if (ov > m2 || (ov == m2 && oi < i2)) { m2 = ov; i2 = oi; }
            }
            if (t == 0) { bvs = m2; bis = i2; }
        }
        __syncthreads();
        if (idx == bis) v = -2.f;
        if (t == r) cidx[r] = bis;
    }
    __syncthreads();
    if (t < NCAND) {
        int j = cidx[t];
        ct1[t] = t1a[j];
        cx1[t] = x1[j];
        cx2[t] = x2[j];
    }
    if (t == 0) {
        int j = cidx[NCAND - 1];
        ubx[0] = x1[j];
        ubx[1] = x2[j];
        *hardcnt = 0;
    }
}

// ---------------- kernel 4: Wh rows of the 16 candidates -> ELU ----------------
__global__ __launch_bounds__(256) void candwh_kernel(const float* __restrict__ h,
                                                     const float* __restrict__ W,
                                                     const int* __restrict__ cidx,
                                                     float* __restrict__ celu) {
    __shared__ float hl[FIN];
    const int b = blockIdx.x, t = threadIdx.x;
    const int row = cidx[b];
    ((float2*)hl)[t] = ((const float2*)&h[(ll)row * FIN])[t];
    __syncthreads();
    float acc = 0.f;
#pragma unroll 8
    for (int k = 0; k < FIN; ++k) acc = fmaf(hl[k], W[k * FOUT + t], acc);
    celu[b * FOUT + t] = acc > 0.f ? acc : expm1f(acc);
}

// ---------------- kernel 4b: init hard-row accumulators ----------------
__global__ __launch_bounds__(256) void hardinit_kernel(float* __restrict__ hacc,
                                                       float* __restrict__ rowsum,
                                                       unsigned* __restrict__ rowmaxenc) {
    int b = blockIdx.x, t = threadIdx.x;
    hacc[b * FIN + t] = 0.f;
    hacc[b * FIN + t + 256] = 0.f;
    if (t == 0) { rowsum[b] = 0.f; rowmaxenc[b] = 0u; }
}

// ---------------- kernel 5: classify rows; write easy rows (one wave per row) ----------------
__global__ __launch_bounds__(256) void classify_kernel(
    const float* __restrict__ params, const int* __restrict__ adj,
    const int* __restrict__ cidx, const float* __restrict__ ct1,
    const float* __restrict__ cx1, const float* __restrict__ cx2,
    const float* __restrict__ ubx, const float* __restrict__ w1, const float* __restrict__ w2,
    const float* __restrict__ hn, const float* __restrict__ wfrob2,
    const unsigned* __restrict__ hnmaxbits, const float* __restrict__ celu,
    int* __restrict__ hardcnt, int* __restrict__ hardlist, float* __restrict__ out) {
    const int i = (blockIdx.x << 2) + (threadIdx.x >> 6);   // one 64-lane wave per row
    const int lane = threadIdx.x & 63;
    const bool valid = lane < NCAND;

    int   cj  = valid ? cidx[lane] : 0;
    float cT  = valid ? ct1[lane] : -1.f;
    float cX1 = valid ? cx1[lane] : 0.f;
    float cX2 = valid ? cx2[lane] : 0.f;
    int ad = valid ? adj[(ll)i * N + cj] : 0;
    unsigned long long m = __ballot(ad > 0);

    float w1i = w1[i], w2i = w2[i];
    bool hard = false;
    int f = -1;
    if (m == 0ull) {
        hard = true;   // no adjacent candidate -> exact fallback
    } else {
        f = __ffsll(m) - 1;
        float t1f = __shfl(cT, f, 64);
        float x1f = __shfl(cX1, f, 64);
        float x2f = __shfl(cX2, f, 64);
        float lastT = __shfl(cT, NCAND - 1, 64);
        // bit-tie among adjacent candidates, or tie with list boundary -> fallback
        unsigned long long tm = __ballot(ad > 0 && (cT == t1f));
        if (__popcll(tm) > 1 || t1f == lastT) hard = true;
        float Lx1 = w1i * x1f + w2i * x2f;
        unsigned long long m2 = m & ~(1ull << f);
        float Lx2 = -INFINITY;
        if (m2 != 0ull) {
            int s2 = __ffsll(m2) - 1;
            Lx2 = w1i * __shfl(cX1, s2, 64) + w2i * __shfl(cX2, s2, 64);
        }
        float ub  = w1i * ubx[0] + w2i * ubx[1];   // bound for ALL non-candidate columns
        float alt = fmaxf(Lx2, ub);
        float wf  = sqrtf(*wfrob2);
        float hmx = __uint_as_float(*hnmaxbits);
        // |a*G| <= a*(||h_i|| |W|_F)*(||h_j|| |W|_F); 2x both sides; 2% f32 inflation;
        // +100 abs slack; relative slack for our-vs-ref exp/product rounding
        float margin = 2.04f * params[0] * (hn[i] * wf) * (hmx * wf)
                     + 100.0f + 1e-5f * fabsf(Lx1);
        if (!(Lx1 - alt > margin)) hard = true;    // NaN-safe: NaN -> hard
    }
    if (hard) {
        if (lane == 0) { int p = atomicAdd(hardcnt, 1); hardlist[p] = i; }
        return;
    }
    // easy: softmax exactly one-hot at candidate rank f -> out = ELU(Wh[cand_f])
    float4 v = ((const float4*)&celu[(ll)f * FOUT])[lane];
    ((float4*)&out[(ll)i * FOUT])[lane] = v;
}

// ---------------- kernel 6a: hard rows — u_h = W (W^T h_i) ----------------
__global__ __launch_bounds__(256) void hardprep_kernel(
    const float* __restrict__ h, const float* __restrict__ W,
    const int* __restrict__ hardcnt, const int* __restrict__ hardlist,
    float* __restrict__ uarr) {
    const int hh = blockIdx.x;
    const int nh = min(*hardcnt, HMAX);
    if (hh >= nh) return;
    const int i = hardlist[hh];
    __shared__ float hl[FIN];
    __shared__ float vl[FOUT];
    const int t = threadIdx.x;
    ((float2*)hl)[t] = ((const float2*)&h[(ll)i * FIN])[t];
    __syncthreads();
    float a = 0.f;
#pragma unroll 8
    for (int k = 0; k < FIN; ++k) a = fmaf(hl[k], W[k * FOUT + t], a);
    vl[t] = a;
    __syncthreads();
    float u0 = 0.f, u1 = 0.f;
#pragma unroll 8
    for (int c = 0; c < FOUT; ++c) {
        float vc = vl[c];
        u0 = fmaf(W[t * FOUT + c], vc, u0);
        u1 = fmaf(W[(t + 256) * FOUT + c], vc, u1);
    }
    uarr[hh * FIN + t] = u0;
    uarr[hh * FIN + t + 256] = u1;
}

// ---------------- kernel 6b: hard rows — logits (h_j . u) + row max ----------------
__global__ __launch_bounds__(256) void hardA_kernel(
    const float* __restrict__ h, const float* __restrict__ params,
    const int* __restrict__ adj, const float* __restrict__ x1, const float* __restrict__ x2,
    const float* __restrict__ w1, const float* __restrict__ w2,
    const int* __restrict__ hardcnt, const int* __restrict__ hardlist,
    const float* __restrict__ uarr, float* __restrict__ ebuf,
    unsigned* __restrict__ rowmaxenc) {
    const int hh = blockIdx.x >> 5;          // 32 chunks of 256 columns
    const int chunk = blockIdx.x & 31;
    const int nh = min(*hardcnt, HMAX);
    if (hh >= nh) return;
    const int i = hardlist[hh];
    __shared__ float uL[FIN];
    __shared__ float sL[256];
    __shared__ float red[4];
    const int t = threadIdx.x, w = t >> 6, lane = t & 63;
    ((float2*)uL)[t] = ((const float2*)&uarr[hh * FIN])[t];
    __syncthreads();
    const float4* uv = (const float4*)&uL[lane * 8];
    float4 u0 = uv[0], u1 = uv[1];
    const int jbase = (chunk << 8) + (w << 6);
    for (int jj = 0; jj < 64; ++jj) {
        int j = jbase + jj;
        const float4* hp = (const float4*)&h[(ll)j * FIN + lane * 8];
        float4 a = hp[0], b = hp[1];
        float s = a.x * u0.x + a.y * u0.y + a.z * u0.z + a.w * u0.w
                + b.x * u1.x + b.y * u1.y + b.z * u1.z + b.w * u1.w;
#pragma unroll
        for (int off = 1; off < 64; off <<= 1) s += __shfl_xor(s, off, 64);
        if (lane == 0) sL[(w << 6) + jj] = s;
    }
    __syncthreads();
    const int j = (chunk << 8) + t;
    float ev = fmaf(params[0], sL[t], params[1]);
    ev = fmaf(w1[i], x1[j], ev);
    ev = fmaf(w2[i], x2[j], ev);
    ev = (adj[(ll)i * N + j] > 0) ? ev : NEGV;
    ebuf[(ll)hh * N + j] = ev;
    float mx = ev;
#pragma unroll
    for (int off = 1; off < 64; off <<= 1) mx = fmaxf(mx, __shfl_xor(mx, off, 64));
    if (lane == 0) red[w] = mx;
    __syncthreads();
    if (t == 0) {
        mx = fmaxf(fmaxf(red[0], red[1]), fmaxf(red[2], red[3]));
        unsigned u = __float_as_uint(mx);
        unsigned enc = (u & 0x80000000u) ? ~u : (u | 0x80000000u);
        atomicMax(&rowmaxenc[hh], enc);
    }
}

// ---------------- kernel 6c: hard rows — exp/sum + weighted h accumulation ----------------
__global__ __launch_bounds__(256) void hardB_kernel(
    const float* __restrict__ h, const int* __restrict__ hardcnt,
    const float* __restrict__ ebuf, const unsigned* __restrict__ rowmaxenc,
    float* __restrict__ rowsum, float* __restrict__ hacc) {
    const int hh = blockIdx.x >> 5;
    const int chunk = blockIdx.x & 31;
    const int nh = min(*hardcnt, HMAX);
    if (hh >= nh) return;
    const int t = threadIdx.x;
    unsigned enc = rowmaxenc[hh];
    unsigned u = (enc & 0x80000000u) ? (enc & 0x7fffffffu) : ~enc;
    const float mx = __uint_as_float(u);
    const int j = (chunk << 8) + t;
    float p = expf(ebuf[(ll)hh * N + j] - mx);
    __shared__ float pl[256];
    pl[t] = p;
    float ps = p;
#pragma unroll
    for (int off = 1; off < 64; off <<= 1) ps += __shfl_xor(ps, off, 64);
    if ((t & 63) == 0) atomicAdd(&rowsum[hh], ps);
    __syncthreads();
    float o0 = 0.f, o1 = 0.f;
    const float* hb = &h[(ll)(chunk << 8) * FIN];
#pragma unroll 4
    for (int jj = 0; jj < 256; ++jj) {
        float pv = pl[jj];
        o0 = fmaf(pv, hb[(ll)jj * FIN + t], o0);
        o1 = fmaf(pv, hb[(ll)jj * FIN + t + 256], o1);
    }
    atomicAdd(&hacc[hh * FIN + t], o0);
    atomicAdd(&hacc[hh * FIN + t + 256], o1);
}

// ---------------- kernel 6d: hard rows — project W^T(hacc/ls), ELU, store ----------------
__global__ __launch_bounds__(256) void hardC_kernel(
    const float* __restrict__ W, const int* __restrict__ hardcnt,
    const int* __restrict__ hardlist, const float* __restrict__ rowsum,
    const float* __restrict__ hacc, float* __restrict__ out) {
    const int hh = blockIdx.x;
    const int nh = min(*hardcnt, HMAX);
    if (hh >= nh) return;
    const int i = hardlist[hh];
    const int t = threadIdx.x;
    __shared__ float hl[FIN];
    float inv = 1.f / rowsum[hh];
    float2 hv = ((const float2*)&hacc[hh * FIN])[t];
    hl[2 * t] = hv.x * inv;
    hl[2 * t + 1] = hv.y * inv;
    __syncthreads();
    float a = 0.f;
#pragma unroll 8
    for (int k = 0; k < FIN; ++k) a = fmaf(hl[k], W[k * FOUT + t], a);
    out[(ll)i * FOUT + t] = a > 0.f ? a : expm1f(a);
}

// ---------------- kernel 6e: serial overflow fallback (hh >= HMAX; normally no-op) ----------------
__global__ __launch_bounds__(256) void hardtail_kernel(
    const float* __restrict__ h, const float* __restrict__ W,
    const float* __restrict__ params, const int* __restrict__ adj,
    const float* __restrict__ x1, const float* __restrict__ x2,
    const float* __restrict__ w1, const float* __restrict__ w2,
    const int* __restrict__ hardcnt, const int* __restrict__ hardlist,
    float* __restrict__ out) {
    __shared__ float hl[FIN];
    __shared__ float vl[FOUT];
    __shared__ float uL[FIN];
    __shared__ float eb[N];        // 32 KB
    __shared__ float red[16];
    const int t = threadIdx.x;
    const int nh = *hardcnt;
    for (int hh = HMAX + blockIdx.x; hh < nh; hh += gridDim.x) {
        const int i = hardlist[hh];
        __syncthreads();
        ((float2*)hl)[t] = ((const float2*)&h[(ll)i * FIN])[t];
        __syncthreads();
        float a = 0.f;
        for (int k = 0; k < FIN; ++k) a = fmaf(hl[k], W[k * FOUT + t], a);
        vl[t] = a;
        __syncthreads();
        float u0 = 0.f, u1 = 0.f;
        for (int c = 0; c < FOUT; ++c) {
            float vc = vl[c];
            u0 = fmaf(W[t * FOUT + c], vc, u0);
            u1 = fmaf(W[(t + 256) * FOUT + c], vc, u1);
        }
        uL[t] = u0; uL[t + 256] = u1;
        __syncthreads();
        const float aC = params[0], cA = params[1], w1i = w1[i], w2i = w2[i];
        for (int j0 = 0; j0 < N; j0 += 256) {
            int j = j0 + t;
            const float* hr = &h[(ll)j * FIN];
            float s = 0.f;
            for (int k = 0; k < FIN; ++k) s = fmaf(hr[k], uL[k], s);
            float ev = fmaf(aC, s, cA);
            ev = fmaf(w1i, x1[j], ev);
            ev = fmaf(w2i, x2[j], ev);
            eb[j] = (adj[(ll)i * N + j] > 0) ? ev : NEGV;
        }
        __syncthreads();
        float mx = -INFINITY;
        for (int j = t; j < N; j += 256) mx = fmaxf(mx, eb[j]);
#pragma unroll
        for (int off = 1; off < 64; off <<= 1) mx = fmaxf(mx, __shfl_xor(mx, off, 64));
        if ((t & 63) == 0) red[t >> 6] = mx;
        __syncthreads();
        mx = fmaxf(fmaxf(red[0], red[1]), fmaxf(red[2], red[3]));
        float ls = 0.f;
        for (int j = t; j < N; j += 256) {
            float p = expf(eb[j] - mx);
            eb[j] = p;
            ls += p;
        }
#pragma unroll
        for (int off = 1; off < 64; off <<= 1) ls += __shfl_xor(ls, off, 64);
        if ((t & 63) == 0) red[8 + (t >> 6)] = ls;
        __syncthreads();
        ls = (red[8] + red[9]) + (red[10] + red[11]);
        float s0 = 0.f, s1 = 0.f;
        for (int j = 0; j < N; ++j) {
            float pv = eb[j];
            s0 = fmaf(pv, h[(ll)j * FIN + 2 * t], s0);
            s1 = fmaf(pv, h[(ll)j * FIN + 2 * t + 1], s1);
        }
        __syncthreads();
        hl[2 * t] = s0 / ls;
        hl[2 * t + 1] = s1 / ls;
        __syncthreads();
        float o = 0.f;
        for (int k = 0; k < FIN; ++k) o = fmaf(hl[k], W[k * FOUT + t], o);
        out[(ll)i * FOUT + t] = o > 0.f ? o : expm1f(o);
    }
}

// ---------------- launch ----------------
extern "C" void kernel_launch(void* const* d_in, const int* in_sizes, int n_in,
                              void* d_out, int out_size, void* d_ws, size_t ws_size,
                              hipStream_t stream) {
    const float* h   = (const float*)d_in[0];
    const float* W   = (const float*)d_in[1];
    const float* Mui = (const float*)d_in[2];
    const int*   adj = (const int*)d_in[3];
    float* out = (float*)d_out;

    float* ws = (float*)d_ws;
    float* t1a    = ws;                         // N
    float* x1     = t1a + N;
    float* x2     = x1 + N;
    float* w1     = x2 + N;
    float* w2     = w1 + N;
    float* hn     = w2 + N;                     // N
    float* wcol1  = hn + N;                     // 512
    float* uarr   = wcol1 + FIN;                // HMAX*512
    float* hacc   = uarr + HMAX * FIN;          // HMAX*512
    float* celu   = hacc + HMAX * FIN;          // 16*256
    float* o1v    = celu + NCAND * FOUT;        // 1024
    float* ct1    = o1v + 1024;                 // 16
    float* cx1    = ct1 + NCAND;
    float* cx2    = cx1 + NCAND;
    float* ubx    = cx2 + NCAND;                // 2
    float* params = ubx + 2;                    // 8
    float* wfrob2 = params + 8;                 // 1
    float* rowsum = wfrob2 + 1;                 // HMAX
    float* ebuf   = rowsum + HMAX;              // HMAX*N
    int*   o1i       = (int*)(ebuf + (ll)HMAX * N); // 1024
    int*   cidx      = o1i + 1024;              // 16
    int*   hardcnt   = cidx + NCAND;            // 1
    unsigned* hnmaxb = (unsigned*)(hardcnt + 1);// 1
    unsigned* rowmaxenc = hnmaxb + 1;           // HMAX
    int*   hardlist  = (int*)(rowmaxenc + HMAX);// N

    params_kernel<<<1, 64, 0, stream>>>(Mui, params, wfrob2, hnmaxb);
    wfrob_kernel<<<FIN * FOUT / 1024, 256, 0, stream>>>(W, wfrob2, wcol1);
    rowstats_kernel<<<N / 4, 256, 0, stream>>>(h, params, wcol1, t1a, x1, x2, w1, w2,
                                               hn, hnmaxb);
    topk1_kernel<<<64, 64, 0, stream>>>(t1a, o1v, o1i);
    topk2_kernel<<<1, 1024, 0, stream>>>(o1v, o1i, t1a, x1, x2,
                                         cidx, ct1, cx1, cx2, ubx, hardcnt);
    candwh_kernel<<<NCAND, 256, 0, stream>>>(h, W, cidx, celu);
    hardinit_kernel<<<HMAX, 256, 0, stream>>>(hacc, rowsum, rowmaxenc);
    classify_kernel<<<N / 4, 256, 0, stream>>>(params, adj, cidx, ct1, cx1, cx2, ubx,
                                               w1, w2, hn, wfrob2, hnmaxb, celu,
                                               hardcnt, hardlist, out);
    hardprep_kernel<<<HMAX, 256, 0, stream>>>(h, W, hardcnt, hardlist, uarr);
    hardA_kernel<<<32 * HMAX, 256, 0, stream>>>(h, params, adj, x1, x2, w1, w2,
                                                hardcnt, hardlist, uarr, ebuf, rowmaxenc);
    hardB_kernel<<<32 * HMAX, 256, 0, stream>>>(h, hardcnt, ebuf, rowmaxenc, rowsum, hacc);
    hardC_kernel<<<HMAX, 256, 0, stream>>>(W, hardcnt, hardlist, rowsum, hacc, out);
    hardtail_kernel<<<64, 256, 0, stream>>>(h, W, params, adj, x1, x2, w1, w2,
                                            hardcnt, hardlist, out);
    (void)n_in; (void)in_sizes; (void)out_size; (void)ws_size;
}